// Round 13
// baseline (394.952 us; speedup 1.0000x reference)
//
#include <hip/hip_runtime.h>

// Problem constants
#define NSAMP 262144
#define CCLS 128
#define DDIM 256
#define EPSF 1e-8f

// ws byte offsets
#define OFF_COUNTS 0u         // 128 * u32
#define OFF_SUMS   2048u      // 128x256 f32 sums (slot-permuted)
#define OFF_G      133120u    // 128x128 f32
#define OFF_W      198656u    // 128x128 f32 (G^-1)
#define OFF_TT     264192u    // 256x128 f32 (T transposed)
#define OFF_B      395264u    // 128x128 f32 (means @ T^T)
#define OFF_ZT     460800u    // 128x128 f32 (W @ B^T)
#define OFF_M      526336u    // 128x128 f32 (B W B^T)
#define OFF_BIG    1644288u   // slabs: 256 x 32768 f32 (128KB each) = 33.5 MB

// ---------------------------------------------------------------------------
// KG: 4 blocks x 1024. Block g computes rows [32g,32g+32) of G = T*T^T and
//     writes T^T chunk g. (verbatim verified)
// ---------------------------------------------------------------------------
extern "C" __global__ __launch_bounds__(1024)
void kg_gram(const float* __restrict__ T, char* __restrict__ ws)
{
    __shared__ float Tl[64][132];
    const int g = blockIdx.x, tid = threadIdx.x;
    float* Tt = (float*)(ws + OFF_TT);
    float* G  = (float*)(ws + OFF_G);
    float a0[8], a1[8];
    #pragma unroll
    for (int j = 0; j < 8; ++j) { a0[j] = 0.f; a1[j] = 0.f; }
    const int Lr = 2 * (tid >> 4);
    const int c0 = 8 * (tid & 15);
    for (int ch = 0; ch < 4; ++ch) {
        for (int i = tid; i < 8192; i += 1024) {
            int cc = i >> 6, dd = i & 63;
            Tl[dd][cc] = T[cc * 256 + ch * 64 + dd];
        }
        __syncthreads();
        if (g == ch) {
            for (int i = tid; i < 8192; i += 1024) {
                int c2 = i & 127, d2 = i >> 7;
                Tt[(ch * 64 + d2) * 128 + c2] = Tl[d2][c2];
            }
        }
        if (tid < 256) {
            for (int dd = 0; dd < 64; ++dd) {
                float r0 = Tl[dd][32 * g + Lr];
                float r1 = Tl[dd][32 * g + Lr + 1];
                float cv[8];
                *(float4*)&cv[0] = *(const float4*)&Tl[dd][c0];
                *(float4*)&cv[4] = *(const float4*)&Tl[dd][c0 + 4];
                #pragma unroll
                for (int j = 0; j < 8; ++j) { a0[j] += r0 * cv[j]; a1[j] += r1 * cv[j]; }
            }
        }
        __syncthreads();
    }
    if (tid < 256) {
        int gr = 32 * g + Lr;
        *(float4*)&G[gr * 128 + c0]           = make_float4(a0[0], a0[1], a0[2], a0[3]);
        *(float4*)&G[gr * 128 + c0 + 4]       = make_float4(a0[4], a0[5], a0[6], a0[7]);
        *(float4*)&G[(gr + 1) * 128 + c0]     = make_float4(a1[0], a1[1], a1[2], a1[3]);
        *(float4*)&G[(gr + 1) * 128 + c0 + 4] = make_float4(a1[4], a1[5], a1[6], a1[7]);
    }
}

// ---------------------------------------------------------------------------
// KA: 256 blocks x 1024 (grid EXACTLY 256 -> no serialized tail; r11's 257th
//     block cost +83us). Fused gated argmax + segment-sum: each gated
//     sample's logits row (512B) + img row (1KB) read exactly once, ungated
//     rows never read. 2-deep pipeline with UNCONDITIONAL clamped-index
//     loads (validity in a bool) so the compiler can emit counted vmcnt.
//     Conflict-free permuted LDS acc (dim 4L+j -> slot j*64+L).
//     Flush = plain float4 stores to own 128KB slab.
// ---------------------------------------------------------------------------
extern "C" __global__ __launch_bounds__(1024)
void ka_fused(const float* __restrict__ logits, const float* __restrict__ img,
              const void* __restrict__ mask, char* __restrict__ ws, int nSlab)
{
    __shared__ float acc[CCLS][DDIM];   // 128 KB
    __shared__ int cnts[CCLS];
    __shared__ int sIsBool;
    const int b = blockIdx.x, tid = threadIdx.x;

    { // init
        float4 z = make_float4(0.f, 0.f, 0.f, 0.f);
        for (int i = tid; i < 8192; i += 1024) ((float4*)acc)[i] = z;
        if (tid < CCLS) cnts[tid] = 0;
        int v = 0;
        if (tid < 64) v = ((const int*)mask)[tid];
        unsigned long long bal = __ballot((unsigned)v > 1u);
        if (tid == 0) sIsBool = (bal != 0ull);
    }
    __syncthreads();
    const bool isBool = (sIsBool != 0);

    const int wave = tid >> 6, lane = tid & 63;
    const int s0 = b * 1024 + wave * 64;
    const float2* lg2 = (const float2*)logits;   // 64 float2 per row
    const float4* im4 = (const float4*)img;      // 64 float4 per row

    int myGate = isBool ? (int)((const unsigned char*)mask)[s0 + lane]
                        : ((const int*)mask)[s0 + lane];
    unsigned long long gm = __ballot(myGate != 0);

    // 2-deep pipeline, unconditional clamped loads (dummy index 0 when empty)
    int  nA = gm ? (int)(__ffsll((long long)gm) - 1) : 0;
    bool vA = (gm != 0ull); gm &= gm - 1;
    float2 lgA = lg2[(size_t)(s0 + nA) * 64 + lane];
    float4 imA = im4[(size_t)(s0 + nA) * 64 + lane];

    int  nB = gm ? (int)(__ffsll((long long)gm) - 1) : 0;
    bool vB = (gm != 0ull); gm &= gm - 1;
    float2 lgB = lg2[(size_t)(s0 + nB) * 64 + lane];
    float4 imB = im4[(size_t)(s0 + nB) * 64 + lane];

    while (vA) {
        float2 lg = lgA; float4 v = imA;
        lgA = lgB; imA = imB; vA = vB;

        int  nC = gm ? (int)(__ffsll((long long)gm) - 1) : 0;
        bool vC = (gm != 0ull); gm &= gm - 1;
        lgB = lg2[(size_t)(s0 + nC) * 64 + lane];
        imB = im4[(size_t)(s0 + nC) * 64 + lane];
        vB = vC;

        // 64-lane argmax (lane holds dims 2L, 2L+1); smaller dim wins ties
        float m = lg.x; int id = 2 * lane;
        if (lg.y > m) { m = lg.y; id = 2 * lane + 1; }
        #pragma unroll
        for (int off = 1; off < 64; off <<= 1) {
            float om = __shfl_xor(m, off);
            int   oi = __shfl_xor(id, off);
            if (om > m || (om == m && oi < id)) { m = om; id = oi; }
        }
        // accumulate (permuted layout: dim 4L+j -> slot j*64+L, conflict-free)
        atomicAdd(&acc[id][lane],       v.x);
        atomicAdd(&acc[id][64 + lane],  v.y);
        atomicAdd(&acc[id][128 + lane], v.z);
        atomicAdd(&acc[id][192 + lane], v.w);
        if (lane == 0) atomicAdd(&cnts[id], 1);
    }
    __syncthreads();

    const float* accF = &acc[0][0];
    if (nSlab == 256) {
        float4* pp = (float4*)((float*)(ws + OFF_BIG) + (size_t)b * 32768);
        for (int i = tid; i < 8192; i += 1024) pp[i] = ((const float4*)accF)[i];
    } else {
        float* slab = (float*)(ws + OFF_BIG) + (size_t)(b % nSlab) * 32768;
        for (int i = tid; i < 32768; i += 1024)
            if (accF[i] != 0.f) unsafeAtomicAdd(&slab[i], accF[i]);
    }
    if (tid < CCLS && cnts[tid]) atomicAdd(&((int*)(ws + OFF_COUNTS))[tid], cnts[tid]);
}

// ---------------------------------------------------------------------------
// KRINV: 33 blocks x 1024. Blocks 0..31: deterministic slab reduction ->
//        sums (slot-permuted), 1024 elems/block. Block 32: Gauss-Jordan
//        inversion of G -> W, 4x4 tile/thread (16 static regs -> cannot
//        spill at any cap). Zero LDS in reduce branch => all 33 blocks
//        resident => GJ fully overlapped with the reduce.
// ---------------------------------------------------------------------------
extern "C" __global__ __launch_bounds__(1024)
void krinv(char* __restrict__ ws, int nSlab)
{
    __shared__ float prA[128], prB[128], pcA[128], pcB[128];
    const int tid = threadIdx.x;

    if (blockIdx.x == 32) {
        // ---- Gauss-Jordan inversion, 1024 threads, 4x4 tiles ----
        const float* G = (const float*)(ws + OFF_G);
        float* W = (float*)(ws + OFF_W);
        float gg[4][4];
        const int r0 = 4 * (tid >> 5), c0 = 4 * (tid & 31);
        #pragma unroll
        for (int ii = 0; ii < 4; ++ii)
            *(float4*)&gg[ii][0] = *(const float4*)&G[(r0 + ii) * 128 + c0];
        if (r0 == 0) {
            #pragma unroll
            for (int j = 0; j < 4; ++j) prA[c0 + j] = gg[0][j];
        }
        if (c0 == 0) {
            #pragma unroll
            for (int i = 0; i < 4; ++i) pcA[r0 + i] = gg[i][0];
        }
        __syncthreads();
        for (int k = 0; k < 128; ++k) {
            const float* pr = (k & 1) ? prB : prA;
            const float* pc = (k & 1) ? pcB : pcA;
            float rinv = 1.0f / pr[k];
            float4 ra = *(const float4*)&pr[c0];
            float4 fa = *(const float4*)&pc[r0];
            float rf[4] = { ra.x, ra.y, ra.z, ra.w };
            float fcv[4] = { fa.x, fa.y, fa.z, fa.w };
            #pragma unroll
            for (int j = 0; j < 4; ++j) rf[j] = (c0 + j == k) ? rinv : rf[j] * rinv;
            #pragma unroll
            for (int i = 0; i < 4; ++i) {
                if (r0 + i == k) {
                    #pragma unroll
                    for (int j = 0; j < 4; ++j) gg[i][j] = rf[j];
                } else {
                    float f = fcv[i];
                    #pragma unroll
                    for (int j = 0; j < 4; ++j) {
                        float base = (c0 + j == k) ? 0.0f : gg[i][j];
                        gg[i][j] = base - f * rf[j];
                    }
                }
            }
            const int kn = k + 1;
            if (kn < 128) {
                float* prn = (kn & 1) ? prB : prA;
                float* pcn = (kn & 1) ? pcB : pcA;
                #pragma unroll
                for (int ii = 0; ii < 4; ++ii) {
                    if (r0 + ii == kn) {
                        #pragma unroll
                        for (int j = 0; j < 4; ++j) prn[c0 + j] = gg[ii][j];
                    }
                }
                #pragma unroll
                for (int jj = 0; jj < 4; ++jj) {
                    if (c0 + jj == kn) {
                        #pragma unroll
                        for (int i = 0; i < 4; ++i) pcn[r0 + i] = gg[i][jj];
                    }
                }
            }
            __syncthreads();
        }
        #pragma unroll
        for (int ii = 0; ii < 4; ++ii)
            *(float4*)&W[(r0 + ii) * 128 + c0] = *(float4*)&gg[ii][0];
        return;
    }

    // ---- slab-reduce blocks ----
    const int idx = blockIdx.x * 1024 + tid;   // [0, 32768)
    const float* p = (const float*)(ws + OFF_BIG) + idx;
    float a = 0.f;
    for (int r = 0; r < nSlab; ++r) a += p[(size_t)r * 32768];
    ((float*)(ws + OFF_SUMS))[idx] = a;
}

// K4: B = (sums/counts) @ T^T  (mean-divide fused; unpermutes slot layout:
//     slot s -> dim 4*(s&63) + (s>>6))
extern "C" __global__ __launch_bounds__(128)
void k4_B(char* __restrict__ ws)
{
    __shared__ float mr[256];
    const int c = blockIdx.x, j = threadIdx.x;
    const float* sums = (const float*)(ws + OFF_SUMS);
    const int* counts = (const int*)(ws + OFF_COUNTS);
    const float* Tt = (const float*)(ws + OFF_TT);
    float rcp = 1.0f / fmaxf((float)counts[c], 1.0f);
    int s0 = j, s1 = j + 128;
    mr[4 * (s0 & 63) + (s0 >> 6)] = sums[c * 256 + s0] * rcp;
    mr[4 * (s1 & 63) + (s1 >> 6)] = sums[c * 256 + s1] * rcp;
    __syncthreads();
    float a = 0.f;
    #pragma unroll 8
    for (int d = 0; d < 256; ++d) a += mr[d] * Tt[d * 128 + j];
    ((float*)(ws + OFF_B))[c * 128 + j] = a;
}

// K5: Zt = (B @ W)^T = W @ B^T   (W symmetric)
extern "C" __global__ __launch_bounds__(128)
void k5_Z(char* __restrict__ ws)
{
    __shared__ float bc[128];
    const int c = blockIdx.x, j = threadIdx.x;
    const float* B = (const float*)(ws + OFF_B);
    const float* W = (const float*)(ws + OFF_W);
    bc[j] = B[c * 128 + j];
    __syncthreads();
    float a = 0.f;
    #pragma unroll 8
    for (int k = 0; k < 128; ++k) a += bc[k] * W[k * 128 + j];
    ((float*)(ws + OFF_ZT))[j * 128 + c] = a;
}

// K6: M = B @ Zt = B W B^T
extern "C" __global__ __launch_bounds__(128)
void k6_M(char* __restrict__ ws)
{
    __shared__ float bc[128];
    const int c = blockIdx.x, j = threadIdx.x;
    const float* B = (const float*)(ws + OFF_B);
    const float* Zt = (const float*)(ws + OFF_ZT);
    bc[j] = B[c * 128 + j];
    __syncthreads();
    float a = 0.f;
    #pragma unroll 8
    for (int k = 0; k < 128; ++k) a += bc[k] * Zt[k * 128 + j];
    ((float*)(ws + OFF_M))[c * 128 + j] = a;
}

// K7: loss
extern "C" __global__ __launch_bounds__(256)
void k7_loss(char* __restrict__ ws, float* __restrict__ out)
{
    __shared__ float norms[128];
    __shared__ int pres[128];
    __shared__ float wsum[4];
    const int tid = threadIdx.x;
    const float* M = (const float*)(ws + OFF_M);
    const int* counts = (const int*)(ws + OFF_COUNTS);
    if (tid < 128) {
        int p = counts[tid] > 0;
        pres[tid] = p;
        norms[tid] = sqrtf(p ? M[tid * 129] : 1.0f);
    }
    __syncthreads();
    float ls = 0.f;
    for (int idx = tid; idx < 16384; idx += 256) {
        int c = idx >> 7, j = idx & 127;
        if (c != j && pres[c] && pres[j])
            ls += 1.0f - M[idx] / ((norms[c] + EPSF) * (norms[j] + EPSF));
    }
    #pragma unroll
    for (int off = 32; off > 0; off >>= 1) ls += __shfl_down(ls, off);
    if ((tid & 63) == 0) wsum[tid >> 6] = ls;
    __syncthreads();
    if (tid == 0) {
        int np = 0;
        for (int c = 0; c < 128; ++c) np += pres[c];
        float tot = wsum[0] + wsum[1] + wsum[2] + wsum[3];
        out[0] = (np >= 2) ? tot : 0.0f;
    }
}

// ---------------------------------------------------------------------------
extern "C" void kernel_launch(void* const* d_in, const int* in_sizes, int n_in,
                              void* d_out, int out_size, void* d_ws, size_t ws_size,
                              hipStream_t stream)
{
    const float* logits = (const float*)d_in[0];
    const float* img    = (const float*)d_in[1];
    const float* T      = (const float*)d_in[2];
    const void*  mask   = d_in[3];
    char* ws = (char*)d_ws;

    size_t avail = (ws_size > (size_t)OFF_BIG) ? ws_size - OFF_BIG : 0;
    int nSlab = (int)(avail / 131072);   // 128 KB per slab
    if (nSlab > 256) nSlab = 256;
    if (nSlab < 1) nSlab = 1;

    hipMemsetAsync(ws + OFF_COUNTS, 0, 512, stream);
    if (nSlab < 256)
        hipMemsetAsync(ws + OFF_BIG, 0, (size_t)nSlab * 131072, stream);

    kg_gram<<<4, 1024, 0, stream>>>(T, ws);                      // G + T^T
    ka_fused<<<256, 1024, 0, stream>>>(logits, img, mask, ws, nSlab); // fused pass
    krinv<<<33, 1024, 0, stream>>>(ws, nSlab);                   // reduce ∥ GJ inv
    k4_B<<<128, 128, 0, stream>>>(ws);
    k5_Z<<<128, 128, 0, stream>>>(ws);
    k6_M<<<128, 128, 0, stream>>>(ws);
    k7_loss<<<1, 256, 0, stream>>>(ws, (float*)d_out);
}

// Round 14
// 351.964 us; speedup vs baseline: 1.1221x; 1.1221x over previous
//
#include <hip/hip_runtime.h>

// Problem constants
#define NSAMP 262144
#define CCLS 128
#define DDIM 256
#define EPSF 1e-8f

// ws byte offsets
#define OFF_COUNTS 0u         // 128 * u32
#define OFF_SUMS   2048u      // 128x256 f32 sums (natural layout)
#define OFF_G      133120u    // 128x128 f32
#define OFF_W      198656u    // 128x128 f32 (G^-1)
#define OFF_TT     264192u    // 256x128 f32 (T transposed)
#define OFF_B      395264u    // 128x128 f32 (means @ T^T)
#define OFF_ZT     460800u    // 128x128 f32 (W @ B^T)
#define OFF_M      526336u    // 128x128 f32 (B W B^T)
#define OFF_LAB    1048576u   // 262144 u8 labels (255 = ungated)
#define OFF_BIG    1644288u   // slabs: 256 x 32768 f32 (128KB each) = 33.5 MB

typedef __attribute__((ext_vector_type(8))) short short8;
typedef __attribute__((ext_vector_type(4))) float float4v;

__device__ inline unsigned short bf16_rn(float x) {
    unsigned u = __float_as_uint(x);
    unsigned r = u + 0x7FFFu + ((u >> 16) & 1u);
    return (unsigned short)(r >> 16);
}
__device__ inline float bf16f(unsigned short h) {
    return __uint_as_float((unsigned)h << 16);
}

// ---------------------------------------------------------------------------
// KG: 4 blocks x 1024. Block g computes rows [32g,32g+32) of G = T*T^T and
//     writes T^T chunk g. (verbatim verified)
// ---------------------------------------------------------------------------
extern "C" __global__ __launch_bounds__(1024)
void kg_gram(const float* __restrict__ T, char* __restrict__ ws)
{
    __shared__ float Tl[64][132];
    const int g = blockIdx.x, tid = threadIdx.x;
    float* Tt = (float*)(ws + OFF_TT);
    float* G  = (float*)(ws + OFF_G);
    float a0[8], a1[8];
    #pragma unroll
    for (int j = 0; j < 8; ++j) { a0[j] = 0.f; a1[j] = 0.f; }
    const int Lr = 2 * (tid >> 4);
    const int c0 = 8 * (tid & 15);
    for (int ch = 0; ch < 4; ++ch) {
        for (int i = tid; i < 8192; i += 1024) {
            int cc = i >> 6, dd = i & 63;
            Tl[dd][cc] = T[cc * 256 + ch * 64 + dd];
        }
        __syncthreads();
        if (g == ch) {
            for (int i = tid; i < 8192; i += 1024) {
                int c2 = i & 127, d2 = i >> 7;
                Tt[(ch * 64 + d2) * 128 + c2] = Tl[d2][c2];
            }
        }
        if (tid < 256) {
            for (int dd = 0; dd < 64; ++dd) {
                float r0 = Tl[dd][32 * g + Lr];
                float r1 = Tl[dd][32 * g + Lr + 1];
                float cv[8];
                *(float4*)&cv[0] = *(const float4*)&Tl[dd][c0];
                *(float4*)&cv[4] = *(const float4*)&Tl[dd][c0 + 4];
                #pragma unroll
                for (int j = 0; j < 8; ++j) { a0[j] += r0 * cv[j]; a1[j] += r1 * cv[j]; }
            }
        }
        __syncthreads();
    }
    if (tid < 256) {
        int gr = 32 * g + Lr;
        *(float4*)&G[gr * 128 + c0]           = make_float4(a0[0], a0[1], a0[2], a0[3]);
        *(float4*)&G[gr * 128 + c0 + 4]       = make_float4(a0[4], a0[5], a0[6], a0[7]);
        *(float4*)&G[(gr + 1) * 128 + c0]     = make_float4(a1[0], a1[1], a1[2], a1[3]);
        *(float4*)&G[(gr + 1) * 128 + c0 + 4] = make_float4(a1[4], a1[5], a1[6], a1[7]);
    }
}

// ---------------------------------------------------------------------------
// KLAB: 1025 blocks x 256 thr, __launch_bounds__(256,2).
//   Block 0: Gauss-Jordan inversion of G -> W (8x8 tile/thread, all-static
//     indexing; (256,2) gives a 256-VGPR budget so the 64-reg gg cannot be
//     occupancy-capped into scratch). ~5 blocks/CU co-residency => GJ is
//     fully overlapped with the 1024 label blocks.
//   Blocks 1..1024: DENSE argmax -> labels[s] (u8, 255=ungated). No serial
//     gated-scan (that pattern cost ~1000cyc/sample in r4-r13). 16-lane
//     group per sample, 4 samples/pass, 2-deep unconditional prefetch.
// ---------------------------------------------------------------------------
extern "C" __global__ __launch_bounds__(256, 2)
void klab(const float* __restrict__ logits, const void* __restrict__ mask,
          char* __restrict__ ws)
{
    __shared__ float prA[128], prB[128], pcA[128], pcB[128];
    __shared__ int sIsBool;
    const int tid = threadIdx.x;

    if (blockIdx.x == 0) {
        // ---- Gauss-Jordan inversion, 256 threads, 8x8 tiles ----
        const float* G = (const float*)(ws + OFF_G);
        float* W = (float*)(ws + OFF_W);
        float gg[8][8];
        const int r0 = 8 * (tid >> 4), c0 = 8 * (tid & 15);
        #pragma unroll
        for (int ii = 0; ii < 8; ++ii) {
            *(float4*)&gg[ii][0] = *(const float4*)&G[(r0 + ii) * 128 + c0];
            *(float4*)&gg[ii][4] = *(const float4*)&G[(r0 + ii) * 128 + c0 + 4];
        }
        if (r0 == 0) {
            #pragma unroll
            for (int j = 0; j < 8; ++j) prA[c0 + j] = gg[0][j];
        }
        if (c0 == 0) {
            #pragma unroll
            for (int i = 0; i < 8; ++i) pcA[r0 + i] = gg[i][0];
        }
        __syncthreads();
        for (int k = 0; k < 128; ++k) {
            const float* pr = (k & 1) ? prB : prA;
            const float* pc = (k & 1) ? pcB : pcA;
            float rinv = 1.0f / pr[k];
            float rf[8], fc[8];
            #pragma unroll
            for (int j = 0; j < 8; ++j) { rf[j] = pr[c0 + j] * rinv; if (c0 + j == k) rf[j] = rinv; }
            #pragma unroll
            for (int i = 0; i < 8; ++i) fc[i] = pc[r0 + i];
            #pragma unroll
            for (int i = 0; i < 8; ++i) {
                if (r0 + i == k) {
                    #pragma unroll
                    for (int j = 0; j < 8; ++j) gg[i][j] = rf[j];
                } else {
                    float f = fc[i];
                    #pragma unroll
                    for (int j = 0; j < 8; ++j) {
                        float base = (c0 + j == k) ? 0.0f : gg[i][j];
                        gg[i][j] = base - f * rf[j];
                    }
                }
            }
            const int kn = k + 1;
            if (kn < 128) {
                float* prn = (kn & 1) ? prB : prA;
                float* pcn = (kn & 1) ? pcB : pcA;
                #pragma unroll
                for (int ii = 0; ii < 8; ++ii) {
                    if (r0 + ii == kn) {
                        #pragma unroll
                        for (int j = 0; j < 8; ++j) prn[c0 + j] = gg[ii][j];
                    }
                }
                #pragma unroll
                for (int jj = 0; jj < 8; ++jj) {
                    if (c0 + jj == kn) {
                        #pragma unroll
                        for (int i = 0; i < 8; ++i) pcn[r0 + i] = gg[i][jj];
                    }
                }
            }
            __syncthreads();
        }
        #pragma unroll
        for (int ii = 0; ii < 8; ++ii) {
            *(float4*)&W[(r0 + ii) * 128 + c0]     = *(float4*)&gg[ii][0];
            *(float4*)&W[(r0 + ii) * 128 + c0 + 4] = *(float4*)&gg[ii][4];
        }
        return;
    }

    // ---- dense label blocks ----
    unsigned char* labels = (unsigned char*)(ws + OFF_LAB);
    { // mask dtype sniff
        int v = 0;
        if (tid < 64) v = ((const int*)mask)[tid];
        unsigned long long bal = __ballot((unsigned)v > 1u);
        if (tid == 0) sIsBool = (bal != 0ull);
    }
    __syncthreads();
    const bool isBool = (sIsBool != 0);

    const int wave = tid >> 6, lane = tid & 63;
    const int base = (blockIdx.x - 1) * 256 + wave * 64;   // 64 samples per wave

    int gv = isBool ? (int)((const unsigned char*)mask)[base + lane]
                    : ((const int*)mask)[base + lane];
    unsigned long long gmask = __ballot(gv != 0);

    const int smp = lane >> 4;          // which of 4 samples in the group
    const int c4  = 4 * (lane & 15);    // column base within row
    const float4* lp4 = (const float4*)logits;   // 32 float4 per row

    size_t r0i = (size_t)(base + smp) * 32 + (c4 >> 2);
    size_t r1i = (size_t)(base + 4 + smp) * 32 + (c4 >> 2);
    float4 a0 = lp4[r0i], b0 = lp4[r0i + 16];
    float4 a1 = lp4[r1i], b1 = lp4[r1i + 16];

    #pragma unroll 1
    for (int g = 0; g < 16; ++g) {
        float4 ca = a0, cb = b0;
        a0 = a1; b0 = b1;
        int pg = (g + 2 < 16) ? g + 2 : 15;          // clamped -> loads unconditional
        size_t rpi = (size_t)(base + 4 * pg + smp) * 32 + (c4 >> 2);
        a1 = lp4[rpi]; b1 = lp4[rpi + 16];

        float m = ca.x; int id = c4;
        if (ca.y > m) { m = ca.y; id = c4 + 1; }
        if (ca.z > m) { m = ca.z; id = c4 + 2; }
        if (ca.w > m) { m = ca.w; id = c4 + 3; }
        if (cb.x > m) { m = cb.x; id = 64 + c4; }
        if (cb.y > m) { m = cb.y; id = 64 + c4 + 1; }
        if (cb.z > m) { m = cb.z; id = 64 + c4 + 2; }
        if (cb.w > m) { m = cb.w; id = 64 + c4 + 3; }
        #pragma unroll
        for (int off = 1; off < 16; off <<= 1) {
            float om = __shfl_xor(m, off);
            int   oi = __shfl_xor(id, off);
            if (om > m || (om == m && oi < id)) { m = om; id = oi; }
        }
        if ((lane & 15) == 0) {
            int s = base + 4 * g + smp;
            bool gt = (gmask >> (4 * g + smp)) & 1ull;
            labels[s] = gt ? (unsigned char)id : (unsigned char)255;
        }
    }
}

// ---------------------------------------------------------------------------
// KMM: 256 blocks x 1024. Segment-sum as a dense MFMA matmul:
//     sums = one_hot(labels)^T @ img. A-frags synthesized IN REGISTERS from
//     labels (no ballot/ffs/atomics in the hot loop); B = img as bf16 hi+lo
//     (|err| <= 2^-18|x|) staged in LDS; fp32 MFMA accumulate.
//     Fragment mapping (m97-verified): A/B idx=l&15, k=(l>>4)*8+j;
//     C/D row=(l>>4)*4+r, col=l&15. Wave w owns output cols [16w,16w+16).
//     Label 255 (ungated) matches no row -> contributes zero.
//     Flush: plain stores to own 128KB slab (natural [c][d] layout) +
//     deterministic int atomics for counts.
// ---------------------------------------------------------------------------
extern "C" __global__ __launch_bounds__(1024)
void kmm(const float* __restrict__ img, char* __restrict__ ws, int nSlab)
{
    __shared__ unsigned short bhi[32][260];   // padded: 520B rows, 8B-aligned
    __shared__ unsigned short blo[32][260];
    __shared__ unsigned char lab[1024];
    __shared__ int cnts[128];
    const int tid = threadIdx.x, b = blockIdx.x;
    const int wave = tid >> 6, lane = tid & 63;
    const int l15 = lane & 15, kg8 = (lane >> 4) * 8;
    const unsigned char* labels = (const unsigned char*)(ws + OFF_LAB);

    if (tid < 128) cnts[tid] = 0;
    lab[tid] = labels[b * 1024 + tid];
    __syncthreads();
    {
        int lb = lab[tid];
        if (lb < 128) atomicAdd(&cnts[lb], 1);
    }

    float4v acc[8];
    #pragma unroll
    for (int t = 0; t < 8; ++t) acc[t] = (float4v)0.f;

    const float4* im4 = (const float4*)img;
    const size_t base4 = (size_t)b * 16384;   // 1024 rows * 64 float4

    // preload chunk 0 into registers
    float4 f0 = im4[base4 + tid];
    float4 f1 = im4[base4 + tid + 1024];

    #pragma unroll 1
    for (int ch = 0; ch < 32; ++ch) {
        // convert + write current chunk to LDS
        {
            int i0 = tid, i1 = tid + 1024;
            int s0 = i0 >> 6, c0 = (i0 & 63) * 4;
            int s1 = i1 >> 6, c1 = (i1 & 63) * 4;
            ushort4 h0, l0, h1, l1;
            h0.x = bf16_rn(f0.x); l0.x = bf16_rn(f0.x - bf16f(h0.x));
            h0.y = bf16_rn(f0.y); l0.y = bf16_rn(f0.y - bf16f(h0.y));
            h0.z = bf16_rn(f0.z); l0.z = bf16_rn(f0.z - bf16f(h0.z));
            h0.w = bf16_rn(f0.w); l0.w = bf16_rn(f0.w - bf16f(h0.w));
            h1.x = bf16_rn(f1.x); l1.x = bf16_rn(f1.x - bf16f(h1.x));
            h1.y = bf16_rn(f1.y); l1.y = bf16_rn(f1.y - bf16f(h1.y));
            h1.z = bf16_rn(f1.z); l1.z = bf16_rn(f1.z - bf16f(h1.z));
            h1.w = bf16_rn(f1.w); l1.w = bf16_rn(f1.w - bf16f(h1.w));
            *(ushort4*)&bhi[s0][c0] = h0; *(ushort4*)&blo[s0][c0] = l0;
            *(ushort4*)&bhi[s1][c1] = h1; *(ushort4*)&blo[s1][c1] = l1;
        }
        // issue next-chunk loads (clamped -> unconditional)
        {
            int chn = (ch + 1 < 32) ? ch + 1 : 31;
            f0 = im4[base4 + chn * 2048 + tid];
            f1 = im4[base4 + chn * 2048 + tid + 1024];
        }
        __syncthreads();

        // my 8 k-labels for this chunk
        int myk[8];
        #pragma unroll
        for (int j = 0; j < 8; ++j) myk[j] = lab[ch * 32 + kg8 + j];

        // B-frags (hi/lo)
        short8 fh, fl;
        #pragma unroll
        for (int j = 0; j < 8; ++j) {
            fh[j] = (short)bhi[kg8 + j][wave * 16 + l15];
            fl[j] = (short)blo[kg8 + j][wave * 16 + l15];
        }

        // 8 M-tiles: A = one-hot from labels, register-synthesized
        #pragma unroll
        for (int t = 0; t < 8; ++t) {
            short8 af;
            #pragma unroll
            for (int j = 0; j < 8; ++j)
                af[j] = (short)((myk[j] == t * 16 + l15) ? 0x3F80 : 0);
            acc[t] = __builtin_amdgcn_mfma_f32_16x16x32_bf16(af, fh, acc[t], 0, 0, 0);
            acc[t] = __builtin_amdgcn_mfma_f32_16x16x32_bf16(af, fl, acc[t], 0, 0, 0);
        }
        __syncthreads();   // all reads done before next chunk's writes
    }

    // flush sums (natural [c][d] layout)
    if (nSlab == 256) {
        float* slab = (float*)(ws + OFF_BIG) + (size_t)b * 32768;
        #pragma unroll
        for (int t = 0; t < 8; ++t) {
            int row = t * 16 + (lane >> 4) * 4;
            int col = wave * 16 + l15;
            #pragma unroll
            for (int r = 0; r < 4; ++r)
                slab[(row + r) * 256 + col] = acc[t][r];
        }
    } else {
        float* slab = (float*)(ws + OFF_BIG) + (size_t)(b % nSlab) * 32768;
        #pragma unroll
        for (int t = 0; t < 8; ++t) {
            int row = t * 16 + (lane >> 4) * 4;
            int col = wave * 16 + l15;
            #pragma unroll
            for (int r = 0; r < 4; ++r)
                if (acc[t][r] != 0.f)
                    unsafeAtomicAdd(&slab[(row + r) * 256 + col], acc[t][r]);
        }
    }
    // counts: integer atomics are order-independent -> deterministic
    if (tid < 128 && cnts[tid]) atomicAdd(&((int*)(ws + OFF_COUNTS))[tid], cnts[tid]);
}

// ---------------------------------------------------------------------------
// KR: deterministic slab reduction -> sums[c*256+d]. 32 blocks x 1024 thr.
// ---------------------------------------------------------------------------
extern "C" __global__ __launch_bounds__(1024)
void kr_sums(char* __restrict__ ws, int nSlab)
{
    const int idx = blockIdx.x * 1024 + threadIdx.x;   // [0, 32768)
    const float* p = (const float*)(ws + OFF_BIG) + idx;
    float a = 0.f;
    for (int r = 0; r < nSlab; ++r) a += p[(size_t)r * 32768];
    ((float*)(ws + OFF_SUMS))[idx] = a;
}

// K4: B = (sums/counts) @ T^T  (mean-divide fused)
extern "C" __global__ __launch_bounds__(128)
void k4_B(char* __restrict__ ws)
{
    __shared__ float mr[256];
    const int c = blockIdx.x, j = threadIdx.x;
    const float* sums = (const float*)(ws + OFF_SUMS);
    const int* counts = (const int*)(ws + OFF_COUNTS);
    const float* Tt = (const float*)(ws + OFF_TT);
    float rcp = 1.0f / fmaxf((float)counts[c], 1.0f);
    mr[j] = sums[c * 256 + j] * rcp;
    mr[j + 128] = sums[c * 256 + 128 + j] * rcp;
    __syncthreads();
    float a = 0.f;
    #pragma unroll 8
    for (int d = 0; d < 256; ++d) a += mr[d] * Tt[d * 128 + j];
    ((float*)(ws + OFF_B))[c * 128 + j] = a;
}

// K5: Zt = (B @ W)^T = W @ B^T   (W symmetric)
extern "C" __global__ __launch_bounds__(128)
void k5_Z(char* __restrict__ ws)
{
    __shared__ float bc[128];
    const int c = blockIdx.x, j = threadIdx.x;
    const float* B = (const float*)(ws + OFF_B);
    const float* W = (const float*)(ws + OFF_W);
    bc[j] = B[c * 128 + j];
    __syncthreads();
    float a = 0.f;
    #pragma unroll 8
    for (int k = 0; k < 128; ++k) a += bc[k] * W[k * 128 + j];
    ((float*)(ws + OFF_ZT))[j * 128 + c] = a;
}

// K6: M = B @ Zt = B W B^T
extern "C" __global__ __launch_bounds__(128)
void k6_M(char* __restrict__ ws)
{
    __shared__ float bc[128];
    const int c = blockIdx.x, j = threadIdx.x;
    const float* B = (const float*)(ws + OFF_B);
    const float* Zt = (const float*)(ws + OFF_ZT);
    bc[j] = B[c * 128 + j];
    __syncthreads();
    float a = 0.f;
    #pragma unroll 8
    for (int k = 0; k < 128; ++k) a += bc[k] * Zt[k * 128 + j];
    ((float*)(ws + OFF_M))[c * 128 + j] = a;
}

// K7: loss
extern "C" __global__ __launch_bounds__(256)
void k7_loss(char* __restrict__ ws, float* __restrict__ out)
{
    __shared__ float norms[128];
    __shared__ int pres[128];
    __shared__ float wsum[4];
    const int tid = threadIdx.x;
    const float* M = (const float*)(ws + OFF_M);
    const int* counts = (const int*)(ws + OFF_COUNTS);
    if (tid < 128) {
        int p = counts[tid] > 0;
        pres[tid] = p;
        norms[tid] = sqrtf(p ? M[tid * 129] : 1.0f);
    }
    __syncthreads();
    float ls = 0.f;
    for (int idx = tid; idx < 16384; idx += 256) {
        int c = idx >> 7, j = idx & 127;
        if (c != j && pres[c] && pres[j])
            ls += 1.0f - M[idx] / ((norms[c] + EPSF) * (norms[j] + EPSF));
    }
    #pragma unroll
    for (int off = 32; off > 0; off >>= 1) ls += __shfl_down(ls, off);
    if ((tid & 63) == 0) wsum[tid >> 6] = ls;
    __syncthreads();
    if (tid == 0) {
        int np = 0;
        for (int c = 0; c < 128; ++c) np += pres[c];
        float tot = wsum[0] + wsum[1] + wsum[2] + wsum[3];
        out[0] = (np >= 2) ? tot : 0.0f;
    }
}

// ---------------------------------------------------------------------------
extern "C" void kernel_launch(void* const* d_in, const int* in_sizes, int n_in,
                              void* d_out, int out_size, void* d_ws, size_t ws_size,
                              hipStream_t stream)
{
    const float* logits = (const float*)d_in[0];
    const float* img    = (const float*)d_in[1];
    const float* T      = (const float*)d_in[2];
    const void*  mask   = d_in[3];
    char* ws = (char*)d_ws;

    size_t avail = (ws_size > (size_t)OFF_BIG) ? ws_size - OFF_BIG : 0;
    int nSlab = (int)(avail / 131072);   // 128 KB per slab
    if (nSlab > 256) nSlab = 256;
    if (nSlab < 1) nSlab = 1;

    hipMemsetAsync(ws + OFF_COUNTS, 0, 512, stream);
    if (nSlab < 256)
        hipMemsetAsync(ws + OFF_BIG, 0, (size_t)nSlab * 131072, stream);

    kg_gram<<<4, 1024, 0, stream>>>(T, ws);                 // G + T^T
    klab<<<1025, 256, 0, stream>>>(logits, mask, ws);       // GJ(block0) ∥ dense labels
    kmm<<<256, 1024, 0, stream>>>(img, ws, nSlab);          // MFMA one-hot segsum
    kr_sums<<<32, 1024, 0, stream>>>(ws, nSlab);            // slab reduce -> sums
    k4_B<<<128, 128, 0, stream>>>(ws);
    k5_Z<<<128, 128, 0, stream>>>(ws);
    k6_M<<<128, 128, 0, stream>>>(ws);
    k7_loss<<<1, 256, 0, stream>>>(ws, (float*)d_out);
}